// Round 6
// baseline (54.618 us; speedup 1.0000x reference)
//
#include <hip/hip_runtime.h>
#include <hip/hip_fp16.h>

#define NROWS 16384
#define NG 100
#define NC 10
#define NH 32
#define NS 10
#define GPC 10
#define SLOPE 0.2f
#define BN_EPS 1e-5f

#define EPADH 36           // halfs per LDS emb row (72B stride)
#define RPB 32             // rows per block
#define BLOCK_A 256        // 32 rows * 8 lanes/row
#define NB (NROWS / RPB)   // 512 blocks

// ---- DPP helpers: cross-lane adds on the VALU pipe (no DS ops) ----
// ctrl: 0xB1 quad_perm(1,0,3,2)=xor1 | 0x4E quad_perm(2,3,0,1)=xor2
//       0x141 row_half_mirror (i -> i^7 within octet) | 0x128 row_ror:8 (xor8 within 16)
template<int CTRL>
__device__ __forceinline__ float dpp_add(float v) {
    int x = __builtin_bit_cast(int, v);
    int y = __builtin_amdgcn_update_dpp(0, x, CTRL, 0xF, 0xF, true);
    return v + __builtin_bit_cast(float, y);
}
// all-reduce over each 8-lane row group: masks {1,2,7} are GF(2)-independent
__device__ __forceinline__ float row8_allreduce(float v) {
    v = dpp_add<0xB1>(v);
    v = dpp_add<0x4E>(v);
    v = dpp_add<0x141>(v);
    return v;
}

__global__ __launch_bounds__(BLOCK_A, 2) void gga_main(
    const int* __restrict__ x, const float* __restrict__ emb,
    const float* __restrict__ gene_att, const float* __restrict__ chrom_att,
    const float* __restrict__ W, const float* __restrict__ b,
    float* __restrict__ y, float* __restrict__ P)
{
    __shared__ __half embL[300 * EPADH];   // 21.6 KB
    __shared__ float eL[300];
    __shared__ float WTL[NS * NH];         // WT[s][h]
    __shared__ float bL[NS];
    __shared__ unsigned xpL[RPB * 8];

    const int t = threadIdx.x;
    const int n0 = blockIdx.x * RPB;

    // ---- block setup: one barrier, all parts independent ----
    for (int i = t; i < 2400; i += BLOCK_A) {          // emb f32 -> f16 LDS
        float4 v = reinterpret_cast<const float4*>(emb)[i];
        int f = i << 2;
        int row = f >> 5, h = f & 31;
        __half2 lo = __floats2half2_rn(v.x, v.y);
        __half2 hi = __floats2half2_rn(v.z, v.w);
        uint2 u;
        u.x = __builtin_bit_cast(unsigned, lo);
        u.y = __builtin_bit_cast(unsigned, hi);
        *reinterpret_cast<uint2*>(&embL[row * EPADH + h]) = u;
    }
    for (int i = t; i < NH * NS; i += BLOCK_A) {       // W^T
        int s = i >> 5, h = i & 31;
        WTL[i] = W[h * NS + s];
    }
    if (t < NS) bL[t] = b[t];
    for (int i = t; i < 300; i += BLOCK_A) {           // e-table from global f32 emb
        const int g = i / 3;
        const float* ga = gene_att + (g / GPC) * NH;
        const float* e = emb + i * NH;
        float s = 0.f;
#pragma unroll
        for (int k = 0; k < NH; k += 4) {
            float4 ev = *reinterpret_cast<const float4*>(e + k);
            float4 gv = *reinterpret_cast<const float4*>(ga + k);
            s = fmaf(gv.x, ev.x, s); s = fmaf(gv.y, ev.y, s);
            s = fmaf(gv.z, ev.z, s); s = fmaf(gv.w, ev.w, s);
        }
        const float lk = s > 0.f ? s : SLOPE * s;
        eL[i] = (s != 0.f) ? __expf(lk) : 0.f;
    }
    {   // cooperative x pack: 32 rows x 8 words
        const int r = t >> 3, w = t & 7;
        unsigned pw = 0u;
        if (w < 7) {
            const int4* p = reinterpret_cast<const int4*>(x + (n0 + r) * NG + w * 16);
            const int nv = (w < 6) ? 4 : 1;
#pragma unroll
            for (int i = 0; i < 4; ++i) {
                if (i < nv) {
                    int4 v = p[i];
                    pw |= ((unsigned)v.x & 3u) << (i * 8 + 0);
                    pw |= ((unsigned)v.y & 3u) << (i * 8 + 2);
                    pw |= ((unsigned)v.z & 3u) << (i * 8 + 4);
                    pw |= ((unsigned)v.w & 3u) << (i * 8 + 6);
                }
            }
        }
        xpL[r * 8 + w] = pw;
    }
    __syncthreads();

    // ---- per-row: 8 lanes/row, lane o owns h comps 4o..4o+3 ----
    const int lr = t >> 3;
    const int o = t & 7;
    const int n = n0 + lr;

    const float4 ca = reinterpret_cast<const float4*>(chrom_att)[o];

    const uint4 pa = *reinterpret_cast<const uint4*>(&xpL[lr * 8]);
    const uint4 pb = *reinterpret_cast<const uint4*>(&xpL[lr * 8 + 4]);
    const unsigned pk[8] = {pa.x, pa.y, pa.z, pa.w, pb.x, pb.y, pb.z, pb.w};

    float4 num = {0.f, 0.f, 0.f, 0.f};
    float den = 0.f;

#pragma unroll
    for (int c = 0; c < NC; ++c) {
        float e[GPC];
        uint2 hu[GPC];                      // raw 4 halfs, converted at use
#pragma unroll
        for (int gp = 0; gp < GPC; ++gp) {
            const int g = c * GPC + gp;
            const unsigned xg = (pk[g >> 4] >> ((g & 15) * 2)) & 3u;
            const int r3 = g * 3 + (int)xg;
            e[gp] = eL[r3];                                   // 8-lane broadcast
            hu[gp] = *reinterpret_cast<const uint2*>(&embL[r3 * EPADH + o * 4]);  // ds_read_b64
        }
        float suma = 0.f;
#pragma unroll
        for (int gp = 0; gp < GPC; ++gp) suma += e[gp];
        const float inv = 1.f / fmaxf(suma, 1e-10f);

        float4 ch = {0.f, 0.f, 0.f, 0.f};
#pragma unroll
        for (int gp = 0; gp < GPC; ++gp) {
            float2 a = __half22float2(__builtin_bit_cast(__half2, hu[gp].x));
            float2 d = __half22float2(__builtin_bit_cast(__half2, hu[gp].y));
            ch.x = fmaf(e[gp], a.x, ch.x);
            ch.y = fmaf(e[gp], a.y, ch.y);
            ch.z = fmaf(e[gp], d.x, ch.z);
            ch.w = fmaf(e[gp], d.y, ch.w);
        }
        ch.x = fmaxf(ch.x, 0.f); ch.y = fmaxf(ch.y, 0.f);   // ReLU commutes with +ve scale
        ch.z = fmaxf(ch.z, 0.f); ch.w = fmaxf(ch.w, 0.f);

        float pc = ch.x * ca.x + ch.y * ca.y + ch.z * ca.z + ch.w * ca.w;
        pc = row8_allreduce(pc);          // VALU-only 8-lane reduce
        pc *= inv;                        // catt[n][c]
        const float lc = pc > 0.f ? pc : SLOPE * pc;
        const float ec = __expf(lc);
        const float w = ec * inv;

        num.x = fmaf(w, ch.x, num.x); num.y = fmaf(w, ch.y, num.y);
        num.z = fmaf(w, ch.z, num.z); num.w = fmaf(w, ch.w, num.w);
        den += ec;
    }

    const float invd = 1.f / den;
    const float g0 = fmaxf(num.x * invd, 0.f);
    const float g1 = fmaxf(num.y * invd, 0.f);
    const float g2 = fmaxf(num.z * invd, 0.f);
    const float g3 = fmaxf(num.w * invd, 0.f);

    float ys[NS];
#pragma unroll
    for (int s = 0; s < NS; ++s) {
        const float4 wv = *reinterpret_cast<const float4*>(&WTL[s * NH + o * 4]);
        float p = g0 * wv.x + g1 * wv.y + g2 * wv.z + g3 * wv.w;
        p = row8_allreduce(p);            // VALU-only
        ys[s] = p + bL[s];
    }

    if (o == 0) {
        float2* yp = reinterpret_cast<float2*>(y + n * NS);
#pragma unroll
        for (int s2 = 0; s2 < 5; ++s2) yp[s2] = make_float2(ys[2 * s2], ys[2 * s2 + 1]);
    }

    // BN partials: ys uniform within each 8-lane row; xor8 via DPP (VALU),
    // xor16/xor32 via shfl; lane 0 -> striped global atomics (VMEM pipe).
    const int kstripe = (int)(blockIdx.x & 7);
#pragma unroll
    for (int s = 0; s < NS; ++s) {
        float v  = ys[s];
        float v2 = ys[s] * ys[s];
        v  = dpp_add<0x128>(v);           // xor8 within 16-lane group
        v2 = dpp_add<0x128>(v2);
        v  += __shfl_xor(v, 16);  v2 += __shfl_xor(v2, 16);
        v  += __shfl_xor(v, 32);  v2 += __shfl_xor(v2, 32);
        if ((t & 63) == 0) {
            atomicAdd(&P[kstripe * 64 + s],      v);
            atomicAdd(&P[kstripe * 64 + 32 + s], v2);
        }
    }
}

// ---------------- BN finalize ----------------
__global__ __launch_bounds__(256) void gga_bn(
    float* __restrict__ out, const float* __restrict__ P,
    const float* __restrict__ gamma, const float* __restrict__ beta)
{
    __shared__ float scL[NS], shL[NS];
    const int t = threadIdx.x;
    if (t < NS) {
        float sm = 0.f, sq = 0.f;
#pragma unroll
        for (int k = 0; k < 8; ++k) {
            sm += P[k * 64 + t];
            sq += P[k * 64 + 32 + t];
        }
        const float mu = sm * (1.f / NROWS);
        float var = sq * (1.f / NROWS) - mu * mu;
        var = fmaxf(var, 0.f);
        const float r = rsqrtf(var + BN_EPS);
        scL[t] = gamma[t] * r;
        shL[t] = beta[t] - mu * scL[t];
    }
    __syncthreads();

    const int i4 = (blockIdx.x * 256 + t) * 4;
    float4 v = *reinterpret_cast<const float4*>(out + i4);
    const int s0 = i4 % NS;
    const int s1 = (s0 + 1) % NS, s2 = (s0 + 2) % NS, s3 = (s0 + 3) % NS;
    v.x = fmaf(v.x, scL[s0], shL[s0]);
    v.y = fmaf(v.y, scL[s1], shL[s1]);
    v.z = fmaf(v.z, scL[s2], shL[s2]);
    v.w = fmaf(v.w, scL[s3], shL[s3]);
    *reinterpret_cast<float4*>(out + i4) = v;
}

extern "C" void kernel_launch(void* const* d_in, const int* in_sizes, int n_in,
                              void* d_out, int out_size, void* d_ws, size_t ws_size,
                              hipStream_t stream) {
    const int*   x         = (const int*)d_in[0];
    const float* emb       = (const float*)d_in[1];
    const float* gene_att  = (const float*)d_in[2];
    const float* chrom_att = (const float*)d_in[3];
    const float* W         = (const float*)d_in[4];
    const float* b         = (const float*)d_in[5];
    const float* bn_gamma  = (const float*)d_in[6];
    const float* bn_beta   = (const float*)d_in[7];

    float* y = (float*)d_out;
    float* P = (float*)d_ws;   // 8 stripes * 64 f32 = 2048 B

    hipMemsetAsync(P, 0, 2048, stream);
    gga_main<<<NB, BLOCK_A, 0, stream>>>(
        x, emb, gene_att, chrom_att, W, b, y, P);
    gga_bn<<<(NROWS * NS) / (256 * 4), 256, 0, stream>>>(
        y, P, bn_gamma, bn_beta);
}

// Round 7
// 25.720 us; speedup vs baseline: 2.1236x; 2.1236x over previous
//
#include <hip/hip_runtime.h>
#include <hip/hip_fp16.h>

#define NROWS 16384
#define NG 100
#define NC 10
#define NH 32
#define NS 10
#define GPC 10
#define SLOPE 0.2f
#define BN_EPS 1e-5f

#define EPADH 36           // halfs per LDS emb row (72B stride)
#define RPB 32             // rows per block
#define BLOCK_A 512        // 32 rows * 16 lanes/row  (round-5 geometry: 4 waves/SIMD)
#define NB (NROWS / RPB)   // 512 blocks

// ---- DPP cross-lane add (VALU pipe, ~8cy vs ~120cy ds_bpermute) ----
template<int CTRL>
__device__ __forceinline__ float dpp_add(float v) {
    int x = __builtin_bit_cast(int, v);
    int y = __builtin_amdgcn_update_dpp(0, x, CTRL, 0xF, 0xF, true);
    return v + __builtin_bit_cast(float, y);
}
// all-reduce within each 16-lane row: circular rotates ror 8,4,2,1
// (after the 4 steps every lane holds the full 16-lane sum)
__device__ __forceinline__ float row16_allreduce(float v) {
    v = dpp_add<0x128>(v);  // row_ror:8
    v = dpp_add<0x124>(v);  // row_ror:4
    v = dpp_add<0x122>(v);  // row_ror:2
    v = dpp_add<0x121>(v);  // row_ror:1
    return v;
}

// gather chrom c's 10 e-values + 10 half2 h-fragments into register arrays
#define GATHER(c, earr, harr)                                              \
    _Pragma("unroll")                                                      \
    for (int gp = 0; gp < GPC; ++gp) {                                     \
        const int g_ = (c) * GPC + gp;                                     \
        const unsigned xg_ = (pk[g_ >> 4] >> ((g_ & 15) * 2)) & 3u;        \
        const int r3_ = g_ * 3 + (int)xg_;                                 \
        earr[gp] = eL[r3_];                                                \
        harr[gp] = *reinterpret_cast<const unsigned*>(&embL[r3_ * EPADH + o * 2]); \
    }

#define COMPUTE(earr, harr) do {                                           \
    float suma_ = 0.f;                                                     \
    _Pragma("unroll")                                                      \
    for (int gp = 0; gp < GPC; ++gp) suma_ += earr[gp];                    \
    const float inv_ = 1.f / fmaxf(suma_, 1e-10f);                         \
    float2 ch_ = {0.f, 0.f};                                               \
    _Pragma("unroll")                                                      \
    for (int gp = 0; gp < GPC; ++gp) {                                     \
        float2 hf_ = __half22float2(__builtin_bit_cast(__half2, harr[gp]));\
        ch_.x = fmaf(earr[gp], hf_.x, ch_.x);                              \
        ch_.y = fmaf(earr[gp], hf_.y, ch_.y);                              \
    }                                                                      \
    ch_.x = fmaxf(ch_.x, 0.f);  /* ReLU commutes with +ve 1/suma scale */  \
    ch_.y = fmaxf(ch_.y, 0.f);                                            \
    float pc_ = ch_.x * ca.x + ch_.y * ca.y;                               \
    pc_ = row16_allreduce(pc_);        /* VALU-only reduce */              \
    pc_ *= inv_;                       /* catt[n][c] */                    \
    const float lc_ = pc_ > 0.f ? pc_ : SLOPE * pc_;                       \
    const float ec_ = __expf(lc_);                                         \
    const float w_ = ec_ * inv_;                                          \
    num.x = fmaf(w_, ch_.x, num.x);                                        \
    num.y = fmaf(w_, ch_.y, num.y);                                        \
    den += ec_;                                                            \
} while (0)

template<bool SLOTS>
__global__ __launch_bounds__(BLOCK_A, 4) void gga_main(
    const int* __restrict__ x, const float* __restrict__ emb,
    const float* __restrict__ gene_att, const float* __restrict__ chrom_att,
    const float* __restrict__ W, const float* __restrict__ b,
    float* __restrict__ y, float* __restrict__ P)
{
    __shared__ __half embL[300 * EPADH];   // 21.6 KB
    __shared__ float eL[300];
    __shared__ float WTL[NS * NH];
    __shared__ float bL[NS];
    __shared__ unsigned xpL[RPB * 8];
    __shared__ float sAcc[2 * NS];

    const int t = threadIdx.x;
    const int n0 = blockIdx.x * RPB;

    // ---- block setup (one barrier) ----
    for (int i = t; i < 2400; i += BLOCK_A) {          // emb f32 -> f16 LDS
        float4 v = reinterpret_cast<const float4*>(emb)[i];
        int f = i << 2;
        int row = f >> 5, h = f & 31;
        __half2 lo = __floats2half2_rn(v.x, v.y);
        __half2 hi = __floats2half2_rn(v.z, v.w);
        uint2 u;
        u.x = __builtin_bit_cast(unsigned, lo);
        u.y = __builtin_bit_cast(unsigned, hi);
        *reinterpret_cast<uint2*>(&embL[row * EPADH + h]) = u;
    }
    for (int i = t; i < NH * NS; i += BLOCK_A) {       // W^T
        int s = i >> 5, h = i & 31;
        WTL[i] = W[h * NS + s];
    }
    if (t < NS) bL[t] = b[t];
    if (t < 2 * NS) sAcc[t] = 0.f;
    if (t < 300) {                                     // e-table from global f32 emb
        const int g = t / 3;
        const float* ga = gene_att + (g / GPC) * NH;
        const float* e = emb + t * NH;
        float s = 0.f;
#pragma unroll
        for (int k = 0; k < NH; k += 4) {
            float4 ev = *reinterpret_cast<const float4*>(e + k);
            float4 gv = *reinterpret_cast<const float4*>(ga + k);
            s = fmaf(gv.x, ev.x, s); s = fmaf(gv.y, ev.y, s);
            s = fmaf(gv.z, ev.z, s); s = fmaf(gv.w, ev.w, s);
        }
        const float lk = s > 0.f ? s : SLOPE * s;
        eL[t] = (s != 0.f) ? __expf(lk) : 0.f;
    }
    if (t < 256) {                                     // cooperative x pack
        const int r = t >> 3, w = t & 7;
        unsigned pw = 0u;
        if (w < 7) {
            const int4* p = reinterpret_cast<const int4*>(x + (n0 + r) * NG + w * 16);
            const int nv = (w < 6) ? 4 : 1;            // word 6: trits 96..99 only
#pragma unroll
            for (int i = 0; i < 4; ++i) {
                if (i < nv) {
                    int4 v = p[i];
                    pw |= ((unsigned)v.x & 3u) << (i * 8 + 0);
                    pw |= ((unsigned)v.y & 3u) << (i * 8 + 2);
                    pw |= ((unsigned)v.z & 3u) << (i * 8 + 4);
                    pw |= ((unsigned)v.w & 3u) << (i * 8 + 6);
                }
            }
        }
        xpL[r * 8 + w] = pw;
    }
    __syncthreads();

    // ---- per-row: 16 lanes/row, lane o owns h comps 2o,2o+1 ----
    const int lr = t >> 4;
    const int o = t & 15;
    const int n = n0 + lr;

    const float2 ca = reinterpret_cast<const float2*>(chrom_att)[o];

    const uint4 pa = *reinterpret_cast<const uint4*>(&xpL[lr * 8]);
    const uint4 pb = *reinterpret_cast<const uint4*>(&xpL[lr * 8 + 4]);
    const unsigned pk[8] = {pa.x, pa.y, pa.z, pa.w, pb.x, pb.y, pb.z, pb.w};

    float2 num = {0.f, 0.f};
    float den = 0.f;

    // 2-stage software pipeline: gather chrom c+1 while computing chrom c
    float eA[GPC], eB[GPC];
    unsigned hA[GPC], hB[GPC];
    GATHER(0, eA, hA);
#pragma unroll
    for (int c = 0; c < NC; ++c) {
        if ((c & 1) == 0) {
            if (c + 1 < NC) { GATHER(c + 1, eB, hB); }
            COMPUTE(eA, hA);
        } else {
            if (c + 1 < NC) { GATHER(c + 1, eA, hA); }
            COMPUTE(eB, hB);
        }
    }

    const float invd = 1.f / den;
    const float g0 = fmaxf(num.x * invd, 0.f);
    const float g1 = fmaxf(num.y * invd, 0.f);

    float ys[NS];
#pragma unroll
    for (int s = 0; s < NS; ++s) {
        const float2 wv = *reinterpret_cast<const float2*>(&WTL[s * NH + o * 2]);
        float p = g0 * wv.x + g1 * wv.y;
        p = row16_allreduce(p);          // VALU-only
        ys[s] = p + bL[s];
    }

    if (o == 0) {
        float2* yp = reinterpret_cast<float2*>(y + n * NS);
#pragma unroll
        for (int s2 = 0; s2 < 5; ++s2) yp[s2] = make_float2(ys[2 * s2], ys[2 * s2 + 1]);
    }

    // BN partials: ys uniform across a row's 16 o-lanes; xor16/32 sums the
    // wave's 4 rows exactly once each (no replication scale).
#pragma unroll
    for (int s = 0; s < NS; ++s) {
        float v = ys[s];
        float v2 = ys[s] * ys[s];
        v += __shfl_xor(v, 16);  v2 += __shfl_xor(v2, 16);
        v += __shfl_xor(v, 32);  v2 += __shfl_xor(v2, 32);
        if ((t & 63) == 0) {
            atomicAdd(&sAcc[s], v);
            atomicAdd(&sAcc[NS + s], v2);
        }
    }
    __syncthreads();
    if (t < 2 * NS) {
        if (SLOTS) P[t * NB + blockIdx.x] = sAcc[t];   // plain store, no zeroing
        else       atomicAdd(&P[t], sAcc[t]);          // tiny-ws fallback
    }
}

// ---------------- BN finalize: reduce slots + apply, float4 I/O ----------------
template<bool SLOTS>
__global__ __launch_bounds__(256) void gga_bn(
    float* __restrict__ out, const float* __restrict__ P,
    const float* __restrict__ gamma, const float* __restrict__ beta)
{
    __shared__ float red[2 * NS * 8];
    __shared__ float scL[NS], shL[NS];
    const int t = threadIdx.x;

    if (SLOTS) {
        if (t < 2 * NS * 8) {                      // 160 reducer threads
            const int k = t >> 3, c = t & 7;
            const float4* p4 = reinterpret_cast<const float4*>(P + k * NB + c * 64);
            float s = 0.f;
#pragma unroll
            for (int i = 0; i < 16; ++i) {
                float4 v = p4[i];
                s += v.x + v.y + v.z + v.w;
            }
            red[t] = s;
        }
        __syncthreads();
    }
    if (t < NS) {
        float sm, sq;
        if (SLOTS) {
            sm = 0.f; sq = 0.f;
#pragma unroll
            for (int c = 0; c < 8; ++c) {
                sm += red[t * 8 + c];
                sq += red[(NS + t) * 8 + c];
            }
        } else {
            sm = P[t]; sq = P[NS + t];
        }
        const float mu = sm * (1.f / NROWS);
        float var = sq * (1.f / NROWS) - mu * mu;
        var = fmaxf(var, 0.f);
        const float r = rsqrtf(var + BN_EPS);
        scL[t] = gamma[t] * r;
        shL[t] = beta[t] - mu * scL[t];
    }
    __syncthreads();

    const int i4 = (blockIdx.x * 256 + t) * 4;
    float4 v = *reinterpret_cast<const float4*>(out + i4);
    const int s0 = i4 % NS;
    const int s1 = (s0 + 1) % NS, s2 = (s0 + 2) % NS, s3 = (s0 + 3) % NS;
    v.x = fmaf(v.x, scL[s0], shL[s0]);
    v.y = fmaf(v.y, scL[s1], shL[s1]);
    v.z = fmaf(v.z, scL[s2], shL[s2]);
    v.w = fmaf(v.w, scL[s3], shL[s3]);
    *reinterpret_cast<float4*>(out + i4) = v;
}

extern "C" void kernel_launch(void* const* d_in, const int* in_sizes, int n_in,
                              void* d_out, int out_size, void* d_ws, size_t ws_size,
                              hipStream_t stream) {
    const int*   x         = (const int*)d_in[0];
    const float* emb       = (const float*)d_in[1];
    const float* gene_att  = (const float*)d_in[2];
    const float* chrom_att = (const float*)d_in[3];
    const float* W         = (const float*)d_in[4];
    const float* b         = (const float*)d_in[5];
    const float* bn_gamma  = (const float*)d_in[6];
    const float* bn_beta   = (const float*)d_in[7];

    float* y = (float*)d_out;
    float* P = (float*)d_ws;

    if (ws_size >= (size_t)(2 * NS * NB * sizeof(float))) {
        gga_main<true><<<NB, BLOCK_A, 0, stream>>>(
            x, emb, gene_att, chrom_att, W, b, y, P);
        gga_bn<true><<<(NROWS * NS) / (256 * 4), 256, 0, stream>>>(
            y, P, bn_gamma, bn_beta);
    } else {
        hipMemsetAsync(P, 0, 2 * NS * sizeof(float), stream);
        gga_main<false><<<NB, BLOCK_A, 0, stream>>>(
            x, emb, gene_att, chrom_att, W, b, y, P);
        gga_bn<false><<<(NROWS * NS) / (256 * 4), 256, 0, stream>>>(
            y, P, bn_gamma, bn_beta);
    }
}

// Round 8
// 23.291 us; speedup vs baseline: 2.3450x; 1.1043x over previous
//
#include <hip/hip_runtime.h>
#include <hip/hip_fp16.h>

#define NROWS 16384
#define NG 100
#define NC 10
#define NH 32
#define NS 10
#define GPC 10
#define SLOPE 0.2f
#define BN_EPS 1e-5f

#define RPB 32             // rows per block
#define BLOCK_A 512        // 32 rows * 16 lanes/row (4 waves/SIMD, proven geometry)
#define NB (NROWS / RPB)   // 512 blocks

// ---- DPP cross-lane adds (VALU pipe, no DS ops) ----
template<int CTRL>
__device__ __forceinline__ float dpp_add(float v) {
    int x = __builtin_bit_cast(int, v);
    int y = __builtin_amdgcn_update_dpp(0, x, CTRL, 0xF, 0xF, true);
    return v + __builtin_bit_cast(float, y);
}
// all-reduce within each 16-lane row: row_ror 8,4,2,1 (verified round 7)
__device__ __forceinline__ float row16_allreduce(float v) {
    v = dpp_add<0x128>(v);
    v = dpp_add<0x124>(v);
    v = dpp_add<0x122>(v);
    v = dpp_add<0x121>(v);
    return v;
}

// gather chrom c: ONE ds_read_b64 per gene fetches {h:half2, e:f32}
#define GATHER(c, arr)                                                     \
    _Pragma("unroll")                                                      \
    for (int gp = 0; gp < GPC; ++gp) {                                     \
        const int g_ = (c) * GPC + gp;                                     \
        const unsigned xg_ = (pk[g_ >> 4] >> ((g_ & 15) * 2)) & 3u;        \
        const int r3_ = g_ * 3 + (int)xg_;                                 \
        arr[gp] = cmbL[r3_ * 16 + o];                                      \
    }

#define COMPUTE(arr) do {                                                  \
    float e_[GPC];                                                         \
    _Pragma("unroll")                                                      \
    for (int gp = 0; gp < GPC; ++gp)                                       \
        e_[gp] = __builtin_bit_cast(float, arr[gp].y);                     \
    const float s01_ = (e_[0] + e_[1]) + (e_[2] + e_[3]);                  \
    const float s23_ = (e_[4] + e_[5]) + (e_[6] + e_[7]);                  \
    const float suma_ = (s01_ + s23_) + (e_[8] + e_[9]);                   \
    const float inv_ = 1.f / fmaxf(suma_, 1e-10f);                         \
    float2 ch_ = {0.f, 0.f};                                               \
    _Pragma("unroll")                                                      \
    for (int gp = 0; gp < GPC; ++gp) {                                     \
        float2 hf_ = __half22float2(__builtin_bit_cast(__half2, arr[gp].x));\
        ch_.x = fmaf(e_[gp], hf_.x, ch_.x);                                \
        ch_.y = fmaf(e_[gp], hf_.y, ch_.y);                                \
    }                                                                      \
    ch_.x = fmaxf(ch_.x, 0.f);  /* ReLU commutes with +ve 1/suma scale */  \
    ch_.y = fmaxf(ch_.y, 0.f);                                             \
    float pc_ = ch_.x * ca.x + ch_.y * ca.y;                               \
    pc_ = row16_allreduce(pc_);        /* VALU-only reduce */              \
    pc_ *= inv_;                       /* catt[n][c] */                    \
    const float lc_ = pc_ > 0.f ? pc_ : SLOPE * pc_;                       \
    const float ec_ = __expf(lc_);                                         \
    const float w_ = ec_ * inv_;                                           \
    num.x = fmaf(w_, ch_.x, num.x);                                        \
    num.y = fmaf(w_, ch_.y, num.y);                                        \
    den += ec_;                                                            \
} while (0)

template<bool SLOTS>
__global__ __launch_bounds__(BLOCK_A, 4) void gga_main(
    const int* __restrict__ x, const float* __restrict__ emb,
    const float* __restrict__ gene_att, const float* __restrict__ chrom_att,
    const float* __restrict__ W, const float* __restrict__ b,
    float* __restrict__ y, float* __restrict__ P)
{
    __shared__ uint2 cmbL[300 * 16];   // 38.4 KB: {x = half2 h(2o,2o+1), y = f32 e}
    __shared__ float eL[300];
    __shared__ float WTL[NS * NH];     // WT[s][h]
    __shared__ float bL[NS];
    __shared__ unsigned xpL[RPB * 8];
    __shared__ float sAcc[2 * NS];

    const int t = threadIdx.x;
    const int n0 = blockIdx.x * RPB;

    // ---- phase 0: e-table (global f32), W^T, bias, x-pack (all independent) ----
    if (t < 300) {
        const int g = t / 3;
        const float* ga = gene_att + (g / GPC) * NH;
        const float* e = emb + t * NH;
        float s = 0.f;
#pragma unroll
        for (int k = 0; k < NH; k += 4) {
            float4 ev = *reinterpret_cast<const float4*>(e + k);
            float4 gv = *reinterpret_cast<const float4*>(ga + k);
            s = fmaf(gv.x, ev.x, s); s = fmaf(gv.y, ev.y, s);
            s = fmaf(gv.z, ev.z, s); s = fmaf(gv.w, ev.w, s);
        }
        const float lk = s > 0.f ? s : SLOPE * s;
        eL[t] = (s != 0.f) ? __expf(lk) : 0.f;
    }
    if (t < NH * NS) WTL[t] = W[(t & 31) * NS + (t >> 5)];   // WT[s][h], i = s*32+h
    if (t < NS) bL[t] = b[t];
    if (t < 2 * NS) sAcc[t] = 0.f;
    if (t < 256) {                                     // cooperative x pack
        const int r = t >> 3, w = t & 7;
        unsigned pw = 0u;
        if (w < 7) {
            const int4* p = reinterpret_cast<const int4*>(x + (n0 + r) * NG + w * 16);
            const int nv = (w < 6) ? 4 : 1;            // word 6: trits 96..99 only
#pragma unroll
            for (int i = 0; i < 4; ++i) {
                if (i < nv) {
                    int4 v = p[i];
                    pw |= ((unsigned)v.x & 3u) << (i * 8 + 0);
                    pw |= ((unsigned)v.y & 3u) << (i * 8 + 2);
                    pw |= ((unsigned)v.z & 3u) << (i * 8 + 4);
                    pw |= ((unsigned)v.w & 3u) << (i * 8 + 6);
                }
            }
        }
        xpL[r * 8 + w] = pw;
    }
    __syncthreads();

    // ---- phase 1: build fused {h,e} table (coalesced float2 global reads) ----
#pragma unroll
    for (int i2 = 0; i2 < 10; ++i2) {
        const int i = t + i2 * BLOCK_A;
        if (i < 4800) {                                 // i = r3*16 + o
            float2 hv = reinterpret_cast<const float2*>(emb)[i];
            __half2 h2 = __floats2half2_rn(hv.x, hv.y);
            uint2 en;
            en.x = __builtin_bit_cast(unsigned, h2);
            en.y = __builtin_bit_cast(unsigned, eL[i >> 4]);  // 16-lane broadcast
            cmbL[i] = en;
        }
    }
    __syncthreads();

    // ---- per-row: 16 lanes/row, lane o owns h comps 2o,2o+1 ----
    const int lr = t >> 4;
    const int o = t & 15;
    const int n = n0 + lr;

    const float2 ca = reinterpret_cast<const float2*>(chrom_att)[o];

    const uint4 pa = *reinterpret_cast<const uint4*>(&xpL[lr * 8]);
    const uint4 pb = *reinterpret_cast<const uint4*>(&xpL[lr * 8 + 4]);
    const unsigned pk[8] = {pa.x, pa.y, pa.z, pa.w, pb.x, pb.y, pb.z, pb.w};

    float2 num = {0.f, 0.f};
    float den = 0.f;

    // 2-stage software pipeline: gather chrom c+1 while computing chrom c
    uint2 hA[GPC], hB[GPC];
    GATHER(0, hA);
#pragma unroll
    for (int c = 0; c < NC; ++c) {
        if ((c & 1) == 0) {
            if (c + 1 < NC) { GATHER(c + 1, hB); }
            COMPUTE(hA);
        } else {
            if (c + 1 < NC) { GATHER(c + 1, hA); }
            COMPUTE(hB);
        }
    }

    const float invd = 1.f / den;
    const float g0 = fmaxf(num.x * invd, 0.f);
    const float g1 = fmaxf(num.y * invd, 0.f);

    float ys[NS];
#pragma unroll
    for (int s = 0; s < NS; ++s) {
        const float2 wv = *reinterpret_cast<const float2*>(&WTL[s * NH + o * 2]);
        float p = g0 * wv.x + g1 * wv.y;
        p = row16_allreduce(p);          // VALU-only
        ys[s] = p + bL[s];
    }

    if (o == 0) {
        float2* yp = reinterpret_cast<float2*>(y + n * NS);
#pragma unroll
        for (int s2 = 0; s2 < 5; ++s2) yp[s2] = make_float2(ys[2 * s2], ys[2 * s2 + 1]);
    }

    // BN partials: ys uniform within each 16-lane row. row_bcast15 (0x142)
    // then row_bcast31 (0x143) accumulate the wave's 4 row-groups; lane 63
    // holds the wave total (VALU-only, no shuffles).
#pragma unroll
    for (int s = 0; s < NS; ++s) {
        float v = ys[s];
        float v2 = ys[s] * ys[s];
        v = dpp_add<0x142>(v);  v2 = dpp_add<0x142>(v2);
        v = dpp_add<0x143>(v);  v2 = dpp_add<0x143>(v2);
        if ((t & 63) == 63) {
            atomicAdd(&sAcc[s], v);
            atomicAdd(&sAcc[NS + s], v2);
        }
    }
    __syncthreads();
    if (t < 2 * NS) {
        if (SLOTS) P[t * NB + blockIdx.x] = sAcc[t];   // plain store, no zeroing
        else       atomicAdd(&P[t], sAcc[t]);          // tiny-ws fallback
    }
}

// ---------------- BN finalize: reduce slots + apply, float4 I/O ----------------
template<bool SLOTS>
__global__ __launch_bounds__(256) void gga_bn(
    float* __restrict__ out, const float* __restrict__ P,
    const float* __restrict__ gamma, const float* __restrict__ beta)
{
    __shared__ float red[2 * NS * 8];
    __shared__ float scL[NS], shL[NS];
    const int t = threadIdx.x;

    if (SLOTS) {
        if (t < 2 * NS * 8) {                      // 160 reducer threads
            const int k = t >> 3, c = t & 7;
            const float4* p4 = reinterpret_cast<const float4*>(P + k * NB + c * 64);
            float s = 0.f;
#pragma unroll
            for (int i = 0; i < 16; ++i) {
                float4 v = p4[i];
                s += v.x + v.y + v.z + v.w;
            }
            red[t] = s;
        }
        __syncthreads();
    }
    if (t < NS) {
        float sm, sq;
        if (SLOTS) {
            sm = 0.f; sq = 0.f;
#pragma unroll
            for (int c = 0; c < 8; ++c) {
                sm += red[t * 8 + c];
                sq += red[(NS + t) * 8 + c];
            }
        } else {
            sm = P[t]; sq = P[NS + t];
        }
        const float mu = sm * (1.f / NROWS);
        float var = sq * (1.f / NROWS) - mu * mu;
        var = fmaxf(var, 0.f);
        const float r = rsqrtf(var + BN_EPS);
        scL[t] = gamma[t] * r;
        shL[t] = beta[t] - mu * scL[t];
    }
    __syncthreads();

    const int i4 = (blockIdx.x * 256 + t) * 4;
    float4 v = *reinterpret_cast<const float4*>(out + i4);
    const int s0 = i4 % NS;
    const int s1 = (s0 + 1) % NS, s2 = (s0 + 2) % NS, s3 = (s0 + 3) % NS;
    v.x = fmaf(v.x, scL[s0], shL[s0]);
    v.y = fmaf(v.y, scL[s1], shL[s1]);
    v.z = fmaf(v.z, scL[s2], shL[s2]);
    v.w = fmaf(v.w, scL[s3], shL[s3]);
    *reinterpret_cast<float4*>(out + i4) = v;
}

extern "C" void kernel_launch(void* const* d_in, const int* in_sizes, int n_in,
                              void* d_out, int out_size, void* d_ws, size_t ws_size,
                              hipStream_t stream) {
    const int*   x         = (const int*)d_in[0];
    const float* emb       = (const float*)d_in[1];
    const float* gene_att  = (const float*)d_in[2];
    const float* chrom_att = (const float*)d_in[3];
    const float* W         = (const float*)d_in[4];
    const float* b         = (const float*)d_in[5];
    const float* bn_gamma  = (const float*)d_in[6];
    const float* bn_beta   = (const float*)d_in[7];

    float* y = (float*)d_out;
    float* P = (float*)d_ws;

    if (ws_size >= (size_t)(2 * NS * NB * sizeof(float))) {
        gga_main<true><<<NB, BLOCK_A, 0, stream>>>(
            x, emb, gene_att, chrom_att, W, b, y, P);
        gga_bn<true><<<(NROWS * NS) / (256 * 4), 256, 0, stream>>>(
            y, P, bn_gamma, bn_beta);
    } else {
        hipMemsetAsync(P, 0, 2 * NS * sizeof(float), stream);
        gga_main<false><<<NB, BLOCK_A, 0, stream>>>(
            x, emb, gene_att, chrom_att, W, b, y, P);
        gga_bn<false><<<(NROWS * NS) / (256 * 4), 256, 0, stream>>>(
            y, P, bn_gamma, bn_beta);
    }
}